// Round 9
// baseline (19.267 us; speedup 1.0000x reference)
//
#include <hip/hip_runtime.h>

#define NCL_EPS    1e-12f
#define NCL_POISON 0xAAAAAAAAAAAAAAAAULL
#define NCL_SCALE  134217728.0   // 2^27

// Single kernel node, value-carrying ticket. 64 blocks x 1024 threads
// (16 waves); each half-wave (32 lanes) computes one row's
// 1 - cos(x_i, centers[labels_i]) via float4 loads; 4 rows/wave, loads
// issued breadth-first (R7-proven phase 1). Block partial is encoded as
// 42-bit fixed point (bias +1, scale 2^27) | count 1 in low 22 bits, and
// added into ONE u64 accumulator with a relaxed agent-scope fetch_add.
// Integer adds commute -> bit-deterministic. The block whose returned
// count equals nblocks-1 (base 0 steady-state, or 0xAA poison base) holds
// the complete sum in old+val: it decodes, writes the mean, resets acc.
__global__ __launch_bounds__(1024) void ncl_vticket_kernel(
    const float* __restrict__ x,
    const int* __restrict__ labels,
    const float* __restrict__ centers,
    unsigned long long* __restrict__ acc,   // 1 u64 in d_ws
    float* __restrict__ out,
    int batch, int nblocks)
{
    const int tid  = threadIdx.x;
    const int bid  = blockIdx.x;
    const int wave = tid >> 6;    // 0..15
    const int lane = tid & 63;
    const int half = lane >> 5;   // which half-wave (0/1)
    const int hl   = lane & 31;   // lane within half-wave

    // Two rows per half-wave: rowA, rowB (adjacent rows per wave -> the
    // wave's x-loads cover contiguous 1KB segments).
    const int rowA = bid * 64 + wave * 4 + half;
    const int rowB = rowA + 2;
    const int rA = min(rowA, batch - 1);
    const int rB = min(rowB, batch - 1);
    const float vA = (rowA < batch) ? 1.0f : 0.0f;
    const float vB = (rowB < batch) ? 1.0f : 0.0f;

    // Breadth-first load issue: labels, then all four row loads in flight.
    const int lA = labels[rA];
    const int lB = labels[rB];
    const float4 xvA = reinterpret_cast<const float4*>(x + (size_t)rA * 128)[hl];
    const float4 xvB = reinterpret_cast<const float4*>(x + (size_t)rB * 128)[hl];
    const float4 cvA = reinterpret_cast<const float4*>(centers + (size_t)lA * 128)[hl];
    const float4 cvB = reinterpret_cast<const float4*>(centers + (size_t)lB * 128)[hl];

    float xxA = xvA.x * xvA.x + xvA.y * xvA.y + xvA.z * xvA.z + xvA.w * xvA.w;
    float ccA = cvA.x * cvA.x + cvA.y * cvA.y + cvA.z * cvA.z + cvA.w * cvA.w;
    float xcA = xvA.x * cvA.x + xvA.y * cvA.y + xvA.z * cvA.z + xvA.w * cvA.w;
    float xxB = xvB.x * xvB.x + xvB.y * xvB.y + xvB.z * xvB.z + xvB.w * xvB.w;
    float ccB = cvB.x * cvB.x + cvB.y * cvB.y + cvB.z * cvB.z + cvB.w * cvB.w;
    float xcB = xvB.x * cvB.x + xvB.y * cvB.y + xvB.z * cvB.z + xvB.w * cvB.w;

    #pragma unroll
    for (int off = 16; off >= 1; off >>= 1) {
        xxA += __shfl_xor(xxA, off, 64);
        ccA += __shfl_xor(ccA, off, 64);
        xcA += __shfl_xor(xcA, off, 64);
        xxB += __shfl_xor(xxB, off, 64);
        ccB += __shfl_xor(ccB, off, 64);
        xcB += __shfl_xor(xcB, off, 64);
    }

    float loss_acc = 0.0f;
    if (hl == 0) {
        const float nxA = fmaxf(sqrtf(xxA), NCL_EPS);
        const float ncA = fmaxf(sqrtf(ccA), NCL_EPS);
        const float nxB = fmaxf(sqrtf(xxB), NCL_EPS);
        const float ncB = fmaxf(sqrtf(ccB), NCL_EPS);
        loss_acc = vA * (1.0f - xcA / (nxA * ncA))
                 + vB * (1.0f - xcB / (nxB * ncB));
    }

    __shared__ float sm[32];
    if (hl == 0) sm[wave * 2 + half] = loss_acc;
    __syncthreads();

    if (tid == 0) {
        float s = 0.0f;
        #pragma unroll
        for (int i = 0; i < 32; ++i) s += sm[i];

        // Encode: (s + 1) in 2^27 fixed point (double for exact rounding),
        // shifted past a 22-bit arrival counter.
        const unsigned long long fixed =
            (unsigned long long)((double)s * NCL_SCALE + NCL_SCALE + 0.5);
        const unsigned long long val = (fixed << 22) | 1ULL;

        const unsigned long long old = __hip_atomic_fetch_add(
            acc, val, __ATOMIC_RELAXED, __HIP_MEMORY_SCOPE_AGENT);

        const unsigned long long nb1  = (unsigned long long)(nblocks - 1);
        const unsigned long long cnt  = old & 0x3FFFFFULL;
        const unsigned long long pcnt = (NCL_POISON & 0x3FFFFFULL) + nb1;

        if (cnt == nb1 || cnt == pcnt) {
            const unsigned long long total = old + val;
            const unsigned long long base  = (cnt == pcnt) ? NCL_POISON : 0ULL;
            const unsigned long long sumv  = (total - base) >> 22;
            const double sum = (double)sumv / NCL_SCALE - (double)nblocks;
            out[0] = (float)(sum / (double)batch);
            __hip_atomic_store(acc, 0ULL,
                               __ATOMIC_RELAXED, __HIP_MEMORY_SCOPE_AGENT);
        }
    }
}

extern "C" void kernel_launch(void* const* d_in, const int* in_sizes, int n_in,
                              void* d_out, int out_size, void* d_ws, size_t ws_size,
                              hipStream_t stream) {
    const float* x       = (const float*)d_in[0];
    const int*   labels  = (const int*)d_in[1];
    const float* centers = (const float*)d_in[2];
    float* out = (float*)d_out;

    const int batch   = in_sizes[1];          // 4096
    const int nblocks = (batch + 63) / 64;    // 64

    unsigned long long* acc = (unsigned long long*)d_ws;

    ncl_vticket_kernel<<<nblocks, 1024, 0, stream>>>(
        x, labels, centers, acc, out, batch, nblocks);
}

// Round 10
// 10.613 us; speedup vs baseline: 1.8154x; 1.8154x over previous
//
#include <hip/hip_runtime.h>

#define NCL_EPS 1e-12f

// Single kernel node, flat ticket (R7 structure — best known). 64 blocks x
// 1024 threads (16 waves); each half-wave (32 lanes) computes one row's
// 1 - cos(x_i, centers[labels_i]) via float4 loads; 4 rows/wave, all loads
// issued breadth-first. Wave 0 parallel-reduces the 32 half-wave losses
// (5 shuffle steps, replacing R7's 32 serial adds) -> block partial.
// Block stores partial (agent scope) + takes a u32 ACQ_REL ticket; the 64th
// arrival reduces all partials in fixed order, writes the mean, resets the
// counter. Deterministic: fixed summation order.
__global__ __launch_bounds__(1024) void ncl_ticket64c_kernel(
    const float* __restrict__ x,
    const int* __restrict__ labels,
    const float* __restrict__ centers,
    float* __restrict__ partials,       // [nblocks] in d_ws
    unsigned int* __restrict__ counter, // 1 uint in d_ws (at +1024B)
    float* __restrict__ out,
    int batch, int nblocks)
{
    const int tid  = threadIdx.x;
    const int bid  = blockIdx.x;
    const int wave = tid >> 6;    // 0..15
    const int lane = tid & 63;
    const int half = lane >> 5;   // which half-wave (0/1)
    const int hl   = lane & 31;   // lane within half-wave

    // Two rows per half-wave: rowA, rowB (wave covers 4 consecutive rows ->
    // contiguous 2KB of x per wave).
    const int rowA = bid * 64 + wave * 4 + half;
    const int rowB = rowA + 2;
    const int rA = min(rowA, batch - 1);
    const int rB = min(rowB, batch - 1);
    const float vA = (rowA < batch) ? 1.0f : 0.0f;
    const float vB = (rowB < batch) ? 1.0f : 0.0f;

    // Breadth-first load issue: labels, then all four row loads in flight.
    const int lA = labels[rA];
    const int lB = labels[rB];
    const float4 xvA = reinterpret_cast<const float4*>(x + (size_t)rA * 128)[hl];
    const float4 xvB = reinterpret_cast<const float4*>(x + (size_t)rB * 128)[hl];
    const float4 cvA = reinterpret_cast<const float4*>(centers + (size_t)lA * 128)[hl];
    const float4 cvB = reinterpret_cast<const float4*>(centers + (size_t)lB * 128)[hl];

    float xxA = xvA.x * xvA.x + xvA.y * xvA.y + xvA.z * xvA.z + xvA.w * xvA.w;
    float ccA = cvA.x * cvA.x + cvA.y * cvA.y + cvA.z * cvA.z + cvA.w * cvA.w;
    float xcA = xvA.x * cvA.x + xvA.y * cvA.y + xvA.z * cvA.z + xvA.w * cvA.w;
    float xxB = xvB.x * xvB.x + xvB.y * xvB.y + xvB.z * xvB.z + xvB.w * xvB.w;
    float ccB = cvB.x * cvB.x + cvB.y * cvB.y + cvB.z * cvB.z + cvB.w * cvB.w;
    float xcB = xvB.x * cvB.x + xvB.y * cvB.y + xvB.z * cvB.z + xvB.w * cvB.w;

    #pragma unroll
    for (int off = 16; off >= 1; off >>= 1) {
        xxA += __shfl_xor(xxA, off, 64);
        ccA += __shfl_xor(ccA, off, 64);
        xcA += __shfl_xor(xcA, off, 64);
        xxB += __shfl_xor(xxB, off, 64);
        ccB += __shfl_xor(ccB, off, 64);
        xcB += __shfl_xor(xcB, off, 64);
    }

    float loss_acc = 0.0f;
    if (hl == 0) {
        const float nxA = fmaxf(sqrtf(xxA), NCL_EPS);
        const float ncA = fmaxf(sqrtf(ccA), NCL_EPS);
        const float nxB = fmaxf(sqrtf(xxB), NCL_EPS);
        const float ncB = fmaxf(sqrtf(ccB), NCL_EPS);
        loss_acc = vA * (1.0f - xcA / (nxA * ncA))
                 + vB * (1.0f - xcB / (nxB * ncB));
    }

    __shared__ float sm[32];
    __shared__ unsigned int s_last;
    if (hl == 0) sm[wave * 2 + half] = loss_acc;
    __syncthreads();

    // wave 0: parallel reduce of the 32 half-wave losses (5 shuffle steps)
    if (tid < 64) {
        float s = (tid < 32) ? sm[tid] : 0.0f;
        #pragma unroll
        for (int off = 16; off >= 1; off >>= 1) s += __shfl_xor(s, off, 64);
        if (tid == 0) {
            __hip_atomic_store(&partials[bid], s,
                               __ATOMIC_RELAXED, __HIP_MEMORY_SCOPE_AGENT);
            const unsigned int old = __hip_atomic_fetch_add(
                counter, 1u, __ATOMIC_ACQ_REL, __HIP_MEMORY_SCOPE_AGENT);
            const unsigned int nb1 = (unsigned int)(nblocks - 1);
            // last arrival whether counter started at 0 (steady state; winner
            // resets it) or at the 0xAA poison pattern (first call).
            s_last = (old == nb1 || old == 0xAAAAAAAAu + nb1) ? 1u : 0u;
        }
    }
    __syncthreads();

    if (s_last && tid < 64) {
        float s = (tid < nblocks)
            ? __hip_atomic_load(&partials[tid],
                                __ATOMIC_RELAXED, __HIP_MEMORY_SCOPE_AGENT)
            : 0.0f;
        #pragma unroll
        for (int off = 32; off >= 1; off >>= 1) s += __shfl_xor(s, off, 64);
        if (tid == 0) {
            out[0] = s / (float)batch;
            __hip_atomic_store(counter, 0u,
                               __ATOMIC_RELAXED, __HIP_MEMORY_SCOPE_AGENT);
        }
    }
}

extern "C" void kernel_launch(void* const* d_in, const int* in_sizes, int n_in,
                              void* d_out, int out_size, void* d_ws, size_t ws_size,
                              hipStream_t stream) {
    const float* x       = (const float*)d_in[0];
    const int*   labels  = (const int*)d_in[1];
    const float* centers = (const float*)d_in[2];
    float* out = (float*)d_out;

    const int batch   = in_sizes[1];          // 4096
    const int nblocks = (batch + 63) / 64;    // 64

    float*        partials = (float*)d_ws;
    unsigned int* counter  = (unsigned int*)((char*)d_ws + 1024);

    ncl_ticket64c_kernel<<<nblocks, 1024, 0, stream>>>(
        x, labels, centers, partials, counter, out, batch, nblocks);
}

// Round 11
// 9.628 us; speedup vs baseline: 2.0011x; 1.1023x over previous
//
#include <hip/hip_runtime.h>

#define NCL_EPS 1e-12f

// Single kernel node, u32 value-carrying ticket. 64 blocks x 1024 threads
// (16 waves); each half-wave (32 lanes) computes one row's
// 1 - cos(x_i, centers[labels_i]) via float4 loads; 4 rows/wave, all loads
// issued breadth-first (R7-proven phase 1). Block partial s (in [0,128]) is
// encoded as round(s*1024) << 8 | 1 and added into ONE u32 accumulator with
// a relaxed agent-scope fetch_add. Integer adds commute -> bit-deterministic.
// Low byte counts arrivals (64 max + 0xAA poison base = 234 < 256, never
// carries into the value field); mod-2^32 wraparound cancels in total-base.
// The block whose returned count equals nblocks-1 (base 0 steady state, or
// 0xAA poison base) holds the full sum in old+val: decode, write mean,
// reset. No partial stores, no acquire gather, no fences.
__global__ __launch_bounds__(1024) void ncl_u32ticket_kernel(
    const float* __restrict__ x,
    const int* __restrict__ labels,
    const float* __restrict__ centers,
    unsigned int* __restrict__ acc,     // 1 u32 in d_ws
    float* __restrict__ out,
    int batch, int nblocks)
{
    const int tid  = threadIdx.x;
    const int bid  = blockIdx.x;
    const int wave = tid >> 6;    // 0..15
    const int lane = tid & 63;
    const int half = lane >> 5;   // which half-wave (0/1)
    const int hl   = lane & 31;   // lane within half-wave

    // Two rows per half-wave: rowA, rowB (wave covers 4 consecutive rows).
    const int rowA = bid * 64 + wave * 4 + half;
    const int rowB = rowA + 2;
    const int rA = min(rowA, batch - 1);
    const int rB = min(rowB, batch - 1);
    const float vA = (rowA < batch) ? 1.0f : 0.0f;
    const float vB = (rowB < batch) ? 1.0f : 0.0f;

    // Breadth-first load issue: labels, then all four row loads in flight.
    const int lA = labels[rA];
    const int lB = labels[rB];
    const float4 xvA = reinterpret_cast<const float4*>(x + (size_t)rA * 128)[hl];
    const float4 xvB = reinterpret_cast<const float4*>(x + (size_t)rB * 128)[hl];
    const float4 cvA = reinterpret_cast<const float4*>(centers + (size_t)lA * 128)[hl];
    const float4 cvB = reinterpret_cast<const float4*>(centers + (size_t)lB * 128)[hl];

    float xxA = xvA.x * xvA.x + xvA.y * xvA.y + xvA.z * xvA.z + xvA.w * xvA.w;
    float ccA = cvA.x * cvA.x + cvA.y * cvA.y + cvA.z * cvA.z + cvA.w * cvA.w;
    float xcA = xvA.x * cvA.x + xvA.y * cvA.y + xvA.z * cvA.z + xvA.w * cvA.w;
    float xxB = xvB.x * xvB.x + xvB.y * xvB.y + xvB.z * xvB.z + xvB.w * xvB.w;
    float ccB = cvB.x * cvB.x + cvB.y * cvB.y + cvB.z * cvB.z + cvB.w * cvB.w;
    float xcB = xvB.x * cvB.x + xvB.y * cvB.y + xvB.z * cvB.z + xvB.w * cvB.w;

    #pragma unroll
    for (int off = 16; off >= 1; off >>= 1) {
        xxA += __shfl_xor(xxA, off, 64);
        ccA += __shfl_xor(ccA, off, 64);
        xcA += __shfl_xor(xcA, off, 64);
        xxB += __shfl_xor(xxB, off, 64);
        ccB += __shfl_xor(ccB, off, 64);
        xcB += __shfl_xor(xcB, off, 64);
    }

    float loss_acc = 0.0f;
    if (hl == 0) {
        const float nxA = fmaxf(sqrtf(xxA), NCL_EPS);
        const float ncA = fmaxf(sqrtf(ccA), NCL_EPS);
        const float nxB = fmaxf(sqrtf(xxB), NCL_EPS);
        const float ncB = fmaxf(sqrtf(ccB), NCL_EPS);
        loss_acc = vA * (1.0f - xcA / (nxA * ncA))
                 + vB * (1.0f - xcB / (nxB * ncB));
    }

    __shared__ float sm[32];
    if (hl == 0) sm[wave * 2 + half] = loss_acc;
    __syncthreads();

    // wave 0: parallel reduce of the 32 half-wave losses, then one u32 RMW.
    if (tid < 64) {
        float s = (tid < 32) ? sm[tid] : 0.0f;
        #pragma unroll
        for (int off = 16; off >= 1; off >>= 1) s += __shfl_xor(s, off, 64);

        if (tid == 0) {
            // fixed-point encode: 1024 = 2^10 scale; value field = bits 8..31
            const unsigned int fixed = (unsigned int)(s * 1024.0f + 0.5f);
            const unsigned int val   = (fixed << 8) | 1u;

            const unsigned int old = __hip_atomic_fetch_add(
                acc, val, __ATOMIC_RELAXED, __HIP_MEMORY_SCOPE_AGENT);

            const unsigned int nb1   = (unsigned int)(nblocks - 1);
            const unsigned int cnt   = old & 0xFFu;
            const unsigned int pcnt  = 0xAAu + nb1;

            if (cnt == nb1 || cnt == pcnt) {
                const unsigned int base  = (cnt == pcnt) ? 0xAAAAAAAAu : 0u;
                const unsigned int sumv  = (old + val - base) >> 8;  // mod 2^32 cancels
                out[0] = (float)((double)sumv / 1024.0 / (double)batch);
                __hip_atomic_store(acc, 0u,
                                   __ATOMIC_RELAXED, __HIP_MEMORY_SCOPE_AGENT);
            }
        }
    }
}

extern "C" void kernel_launch(void* const* d_in, const int* in_sizes, int n_in,
                              void* d_out, int out_size, void* d_ws, size_t ws_size,
                              hipStream_t stream) {
    const float* x       = (const float*)d_in[0];
    const int*   labels  = (const int*)d_in[1];
    const float* centers = (const float*)d_in[2];
    float* out = (float*)d_out;

    const int batch   = in_sizes[1];          // 4096
    const int nblocks = (batch + 63) / 64;    // 64

    unsigned int* acc = (unsigned int*)d_ws;

    ncl_u32ticket_kernel<<<nblocks, 1024, 0, stream>>>(
        x, labels, centers, acc, out, batch, nblocks);
}